// Round 6
// baseline (231.679 us; speedup 1.0000x reference)
//
#include <hip/hip_runtime.h>

// diff_lpc2rc: per-row backward Levinson recursion on N=16 fp32 values.
// Rows: 64 * 32768 = 2,097,152. ~268 MB traffic; stream floor ~43 us.
//
// R7: restore memory-level parallelism that the register allocator was
// destroying. Evidence (R5 counters): VALUBusy 20%, HBM 31%, LDS 0,
// occupancy 50% - every pipe idle, kernel pinned at ~80us across five
// structurally different versions, and VGPR_Count=24 while the pipelined
// loop needs ~40+ live regs. The occupancy-targeting pressure heuristic
// (launch_bounds min-waves=8 -> 64-VGPR cap, and similar default before)
// serialized all loads: ~900cy latency taken per tile, no overlap.
// 128 tiles/CU x (900 + 700cy compute) ~= 205k cy ~= 85us == observed.
//
// Changes:
//  1. __launch_bounds__(256, 2): VGPR cap 256. Even ~80 VGPR keeps
//     16 waves/CU - plenty once MLP exists.
//  2. Explicit double-buffer ldb[2][4] (static ping-pong after unroll):
//     tile t+1 loads issue BEFORE tile t's transpose; waitcnt becomes a
//     counted vmcnt, latency hides under ~1000cy of compute.
//  3. sched_barrier(0) after prefetch issue: forbid the scheduler from
//     re-sinking the loads under pressure (R6's silent failure).
//
// Kept (verified): DPP quad_perm butterfly transpose (all DPP executed
// unconditionally - convergent; selection via value selects), deferred-
// scale recursion, coalesced f32x4 loads/stores, no LDS.

constexpr int N = 16;
constexpr int WAVES_PER_WG = 4;     // 256 threads
constexpr int TILES_PER_WAVE = 4;   // 64-row tiles per wave, pipelined

typedef float f32x4 __attribute__((ext_vector_type(4)));

__device__ __forceinline__ float dpp_xor2(float x) {
    // quad_perm [2,3,0,1] = 0x4E : lane q reads lane q^2 within its quad
    const int xi = __float_as_int(x);
    return __int_as_float(__builtin_amdgcn_update_dpp(xi, xi, 0x4E, 0xF, 0xF, true));
}
__device__ __forceinline__ float dpp_xor1(float x) {
    // quad_perm [1,0,3,2] = 0xB1 : lane q reads lane q^1 within its quad
    const int xi = __float_as_int(x);
    return __int_as_float(__builtin_amdgcn_update_dpp(xi, xi, 0xB1, 0xF, 0xF, true));
}

__device__ __forceinline__ void levinson16(float a[N]) {
    // deferred-scale backward Levinson: one fma per element per step;
    // a single scalar inv_s accumulates the 1/(1-k^2) product.
    float inv_s = 1.0f;
#pragma unroll
    for (int i = 1; i < N; ++i) {
        const int len = N - i;
        const float k = a[len] * inv_s;      // true reflection coeff = final out[len]
        a[len] = k;
        const float r = __builtin_amdgcn_rcpf(1.0f - k * k);
        inv_s *= r;
#pragma unroll
        for (int m = 0; m < len / 2; ++m) {
            const int j = len - 1 - m;
            const float am = a[m];
            const float aj = a[j];
            a[m] = __builtin_fmaf(-k, aj, am);
            a[j] = __builtin_fmaf(-k, am, aj);
        }
        if (len & 1) {
            const int mid = len / 2;
            const float t = a[mid];
            a[mid] = __builtin_fmaf(-k, t, t);
        }
    }
    a[0] *= inv_s;
}

__global__ __launch_bounds__(256, 2) void lpc2rc_kernel(const float* __restrict__ x,
                                                        float* __restrict__ out,
                                                        int nrows) {
    const int tid  = threadIdx.x;
    const int lane = tid & 63;
    const bool hi = (lane >> 1) & 1;   // bit1 of quad index
    const bool lo = lane & 1;          // bit0 of quad index

    const f32x4* __restrict__ in4 = (const f32x4*)x;
    f32x4* __restrict__ out4 = (f32x4*)out;

    const long long tile0 =
        ((long long)blockIdx.x * WAVES_PER_WG + (tid >> 6)) * TILES_PER_WAVE;
    const long long row0 = tile0 * 64;

    float a[N];
    float W[4][4];

    if (row0 + (long long)TILES_PER_WAVE * 64 <= (long long)nrows) {
        // ================= fast path: all tiles full, straight-line =========
        f32x4 ldb[2][4];          // double-buffered load regs (static ping-pong)

        // prologue: issue tile 0 loads
        {
            const long long b0 = row0 * 4;
#pragma unroll
            for (int c = 0; c < 4; ++c)
                ldb[0][c] = in4[b0 + (long long)(c * 64 + lane)];
        }

#pragma unroll
        for (int t = 0; t < TILES_PER_WAVE; ++t) {
            const int cur = t & 1;
            const int nxt = cur ^ 1;

            // ---- issue tile t+1 loads BEFORE consuming tile t ----
            if (t + 1 < TILES_PER_WAVE) {
                const long long bn = (row0 + (long long)(t + 1) * 64) * 4;
#pragma unroll
                for (int c = 0; c < 4; ++c)
                    ldb[nxt][c] = in4[bn + (long long)(c * 64 + lane)];
            }
            // pin the prefetch: nothing may be scheduled across this point,
            // so pressure heuristics cannot sink the loads below the compute.
            __builtin_amdgcn_sched_barrier(0);

            // ---- quad transpose (butterfly): lane 4g+q gets row 16q+g ----
#pragma unroll
            for (int e = 0; e < 4; ++e) {
                const float x0 = dpp_xor2(ldb[cur][0][e]);
                const float x1 = dpp_xor2(ldb[cur][1][e]);
                const float x2 = dpp_xor2(ldb[cur][2][e]);
                const float x3 = dpp_xor2(ldb[cur][3][e]);
                W[0][e] = hi ? x2 : ldb[cur][0][e];
                W[1][e] = hi ? x3 : ldb[cur][1][e];
                W[2][e] = hi ? ldb[cur][2][e] : x0;
                W[3][e] = hi ? ldb[cur][3][e] : x1;
            }
#pragma unroll
            for (int e = 0; e < 4; ++e) {
                const float y0 = dpp_xor1(W[0][e]);
                const float y1 = dpp_xor1(W[1][e]);
                const float y2 = dpp_xor1(W[2][e]);
                const float y3 = dpp_xor1(W[3][e]);
                a[0  + e] = lo ? y1 : W[0][e];
                a[4  + e] = lo ? W[1][e] : y0;
                a[8  + e] = lo ? y3 : W[2][e];
                a[12 + e] = lo ? W[3][e] : y2;
            }

            // ---- recursion (covers the in-flight prefetch) ----
            levinson16(a);

            // ---- inverse quad transpose (same butterfly - involution) ----
#pragma unroll
            for (int e = 0; e < 4; ++e) {
                const float x0 = dpp_xor2(a[0  + e]);
                const float x1 = dpp_xor2(a[4  + e]);
                const float x2 = dpp_xor2(a[8  + e]);
                const float x3 = dpp_xor2(a[12 + e]);
                W[0][e] = hi ? x2 : a[0  + e];
                W[1][e] = hi ? x3 : a[4  + e];
                W[2][e] = hi ? a[8  + e] : x0;
                W[3][e] = hi ? a[12 + e] : x1;
            }
            f32x4 st[4];
#pragma unroll
            for (int e = 0; e < 4; ++e) {
                const float y0 = dpp_xor1(W[0][e]);
                const float y1 = dpp_xor1(W[1][e]);
                const float y2 = dpp_xor1(W[2][e]);
                const float y3 = dpp_xor1(W[3][e]);
                st[0][e] = lo ? y1 : W[0][e];
                st[1][e] = lo ? W[1][e] : y0;
                st[2][e] = lo ? y3 : W[2][e];
                st[3][e] = lo ? W[3][e] : y2;
            }

            // ---- coalesced stores (mirror of load distribution) ----
            const long long b4 = (row0 + (long long)t * 64) * 4;
#pragma unroll
            for (int c = 0; c < 4; ++c)
                out4[b4 + (long long)(c * 64 + lane)] = st[c];
        }
    } else {
        // ================= tail path: per-tile guarded, unpipelined =========
        for (int t = 0; t < TILES_PER_WAVE; ++t) {
            const long long r0 = (tile0 + t) * 64;
            if (r0 >= (long long)nrows) return;
            const long long r = r0 + lane;
            if (r < (long long)nrows) {
                f32x4 v0 = in4[r * 4 + 0], v1 = in4[r * 4 + 1],
                      v2 = in4[r * 4 + 2], v3 = in4[r * 4 + 3];
                a[0]=v0.x; a[1]=v0.y; a[2]=v0.z; a[3]=v0.w;
                a[4]=v1.x; a[5]=v1.y; a[6]=v1.z; a[7]=v1.w;
                a[8]=v2.x; a[9]=v2.y; a[10]=v2.z; a[11]=v2.w;
                a[12]=v3.x; a[13]=v3.y; a[14]=v3.z; a[15]=v3.w;
                levinson16(a);
                v0.x=a[0]; v0.y=a[1]; v0.z=a[2]; v0.w=a[3];
                v1.x=a[4]; v1.y=a[5]; v1.z=a[6]; v1.w=a[7];
                v2.x=a[8]; v2.y=a[9]; v2.z=a[10]; v2.w=a[11];
                v3.x=a[12]; v3.y=a[13]; v3.z=a[14]; v3.w=a[15];
                out4[r * 4 + 0] = v0; out4[r * 4 + 1] = v1;
                out4[r * 4 + 2] = v2; out4[r * 4 + 3] = v3;
            }
        }
    }
}

extern "C" void kernel_launch(void* const* d_in, const int* in_sizes, int n_in,
                              void* d_out, int out_size, void* d_ws, size_t ws_size,
                              hipStream_t stream) {
    const float* x = (const float*)d_in[0];
    float* out = (float*)d_out;
    const int nrows = in_sizes[0] / N;                           // 2,097,152
    const int rows_per_wg = 64 * WAVES_PER_WG * TILES_PER_WAVE;  // 1024
    const int grid = (nrows + rows_per_wg - 1) / rows_per_wg;    // 2048
    lpc2rc_kernel<<<grid, 256, 0, stream>>>(x, out, nrows);
}